// Round 7
// baseline (1073.151 us; speedup 1.0000x reference)
//
#include <hip/hip_runtime.h>
#include <hip/hip_bf16.h>

typedef short bf16x8 __attribute__((ext_vector_type(8)));
typedef float f32x4 __attribute__((ext_vector_type(4)));

#define MFMA16(A,B,C) __builtin_amdgcn_mfma_f32_16x16x32_bf16(A,B,C,0,0,0)

static __device__ __forceinline__ unsigned short f2bf(float f) {
  unsigned int u = __float_as_uint(f);
  u += 0x7fffu + ((u >> 16) & 1u);        // round-to-nearest-even
  return (unsigned short)(u >> 16);
}

// ---- LDS layout (bytes), 56 KB total -> 2 blocks/CU with 48KB slack.
// Head-PAIR structure: 4 passes x 2 heads.
// xw  [64 rows][512 B]          : x window bf16, XOR-swizzled (live all passes)
// qk  [2h][64 rows][128 B]      : q bytes 0..63, k bytes 64..127 ; P overlays
// vt  [2h][32 d][128 B(64 tok)] : v transposed ; o4 [64 tok][128 B] overlays
// epilogue reuses [0, 32768) as f32 [64][128] half-tile (two halves)
#define SWZ(row, byte) ((byte) ^ (((row) & 7) << 4))
#define OFF_XW 0
#define OFF_QK 32768
#define OFF_VT 49152
#define LDS_TOTAL 57344

#define NQKV 196608   // 768*256
#define NPROJ 65536   // 256*256

__global__ void convert_w_kernel(const float* __restrict__ qkv_w,
                                 const float* __restrict__ proj_w,
                                 ushort* __restrict__ wsb) {
  int i = blockIdx.x * 256 + threadIdx.x;
  if (i < NQKV) wsb[i] = f2bf(qkv_w[i]);
  else if (i < NQKV + NPROJ) wsb[i] = f2bf(proj_w[i - NQKV]);
}

// Pair-structured fused kernel. Evidence trail:
// R2 (spilled, total regs ~112): occupancy 43.9% at 80KB LDS -> 2x80 fits.
// R5/R6 (vgpr 124-128 + agprs): 24% -> total regs >128 gated waves/SIMD.
// Here: smaller per-phase accumulators (pairs) keep total <=128, and 56KB LDS
// leaves slack. Target: 2 blocks/CU real.
__global__ __launch_bounds__(512, 2)
void swin_fused_kernel(const float* __restrict__ x,
                       const ushort* __restrict__ qkvw,   // [768][256] bf16
                       const ushort* __restrict__ projw,  // [256][256] bf16
                       const float* __restrict__ proj_b,
                       const float* __restrict__ rel_bias, // [8][64][64] f32
                       float* __restrict__ out) {
  extern __shared__ char smem[];

  const int wid = blockIdx.x;          // window id 0..8191
  const int bb_ = wid >> 10;           // batch
  const int wy  = (wid >> 5) & 31;
  const int wx  = wid & 31;
  const int tid  = threadIdx.x;
  const int wave = tid >> 6;           // 0..7
  const int lane = tid & 63;
  const int l16  = lane & 15;
  const int lq   = lane >> 4;          // 0..3

  // ---- phase 0: stage x window [64 tok][256 ch] as bf16 (zero-fill padding)
  #pragma unroll
  for (int it = 0; it < 8; ++it) {
    const int t  = it * 8 + wave;
    const int gr = wy * 8 + (t >> 3);
    const int gc = wx * 8 + (t & 7);
    float4 v = make_float4(0.f, 0.f, 0.f, 0.f);
    if (gr < 250 && gc < 250)
      v = *(const float4*)(x + ((size_t)bb_ * 62500 + (size_t)gr * 250 + gc) * 256 + lane * 4);
    ushort4 bv;
    bv.x = f2bf(v.x); bv.y = f2bf(v.y); bv.z = f2bf(v.z); bv.w = f2bf(v.w);
    *(ushort4*)(smem + OFF_XW + t * 512 + SWZ(t, lane * 8)) = bv;
  }

  f32x4 oacc[4][2];                    // persistent proj accumulator: wave owns cols [wave*32,+32)
  #pragma unroll
  for (int m = 0; m < 4; ++m)
    #pragma unroll
    for (int n = 0; n < 2; ++n)
      oacc[m][n] = f32x4{0.f, 0.f, 0.f, 0.f};

  const float scale = 0.17677669529663687f;  // 32^-0.5
  const int vwave = (wave >= 4) ? 1 : 0;
  const int wsub  = vwave ? (wave - 4) : wave;
  const int qh    = wsub >> 1;          // head (in pair) this wave's QKV tiles target
  const int qhalf = wsub & 1;           // d-half
  const int hl2 = wave >> 2;            // head (in pair) for attention phases
  const int r0  = (wave & 3) * 16;      // row quarter

  #pragma unroll 1
  for (int pass = 0; pass < 4; ++pass) {
    __syncthreads();  // (a) xw ready / prev pass o4+P reads done

    // ---- QKV: output cols = pair's {q(2h x 32), k(2h x 32), v(2h x 32)}.
    // Waves 0-3: one q-tile + one k-tile. Waves 4-7: one v-tile.
    const int njt = vwave ? 1 : 2;
    #pragma unroll 1
    for (int j = 0; j < njt; ++j) {
      const int ty = vwave ? 2 : j;
      const int wrow = ty * 256 + (pass * 2 + qh) * 32 + qhalf * 16 + l16;
      const ushort* bp = qkvw + (size_t)wrow * 256 + lq * 8;

      f32x4 acc[4];
      #pragma unroll
      for (int m = 0; m < 4; ++m) acc[m] = f32x4{0.f, 0.f, 0.f, 0.f};

      #pragma unroll
      for (int kk = 0; kk < 8; ++kk) {
        bf16x8 bf = *(const bf16x8*)(bp + kk * 32);
        #pragma unroll
        for (int m = 0; m < 4; ++m) {
          const int r = m * 16 + l16;
          bf16x8 af = *(const bf16x8*)(smem + OFF_XW + r * 512 + SWZ(r, kk * 64 + lq * 16));
          acc[m] = MFMA16(af, bf, acc[m]);
        }
      }
      const int d = qhalf * 16 + l16;
      if (ty == 2) {
        #pragma unroll
        for (int m = 0; m < 4; ++m) {
          ushort4 pk;
          pk.x = f2bf(acc[m][0]); pk.y = f2bf(acc[m][1]);
          pk.z = f2bf(acc[m][2]); pk.w = f2bf(acc[m][3]);
          const int tok0 = m * 16 + lq * 4;
          *(ushort4*)(smem + OFF_VT + (qh * 32 + d) * 128 + SWZ(d, tok0 * 2)) = pk;
        }
      } else if (ty == 0) {
        #pragma unroll
        for (int m = 0; m < 4; ++m)
          #pragma unroll
          for (int rr = 0; rr < 4; ++rr) {
            const int tok = m * 16 + lq * 4 + rr;
            *(ushort*)(smem + OFF_QK + (qh * 64 + tok) * 128 + SWZ(tok, d * 2)) = f2bf(acc[m][rr] * scale);
          }
      } else {
        #pragma unroll
        for (int m = 0; m < 4; ++m)
          #pragma unroll
          for (int rr = 0; rr < 4; ++rr) {
            const int tok = m * 16 + lq * 4 + rr;
            *(ushort*)(smem + OFF_QK + (qh * 64 + tok) * 128 + SWZ(tok, 64 + d * 2)) = f2bf(acc[m][rr]);
          }
      }
    }
    __syncthreads();  // (b) q/k/vT ready

    // ---- S = Qs*K^T : wave owns head hl2, rows [r0, r0+16)
    f32x4 s[4];
    {
      const int r = r0 + l16;
      bf16x8 qf = *(const bf16x8*)(smem + OFF_QK + (hl2 * 64 + r) * 128 + SWZ(r, lq * 16));
      #pragma unroll
      for (int nt = 0; nt < 4; ++nt) {
        const int kr = nt * 16 + l16;
        bf16x8 kf = *(const bf16x8*)(smem + OFF_QK + (hl2 * 64 + kr) * 128 + SWZ(kr, 64 + lq * 16));
        s[nt] = MFMA16(qf, kf, (f32x4{0.f, 0.f, 0.f, 0.f}));
      }
    }
    __syncthreads();  // (b2) q/k reads done -> P may overlay qk

    // ---- softmax (4 rows/lane), P into qk region
    const float* biasb = rel_bias + (size_t)(pass * 2 + hl2) * 4096;
    float rcp_[4];
    #pragma unroll
    for (int rr = 0; rr < 4; ++rr) {
      const int qrow = r0 + lq * 4 + rr;
      float vmax = -1e30f;
      #pragma unroll
      for (int nt = 0; nt < 4; ++nt) {
        float v = s[nt][rr] + biasb[qrow * 64 + nt * 16 + l16];
        s[nt][rr] = v;
        vmax = fmaxf(vmax, v);
      }
      vmax = fmaxf(vmax, __shfl_xor(vmax, 1));
      vmax = fmaxf(vmax, __shfl_xor(vmax, 2));
      vmax = fmaxf(vmax, __shfl_xor(vmax, 4));
      vmax = fmaxf(vmax, __shfl_xor(vmax, 8));
      float ssum = 0.f;
      #pragma unroll
      for (int nt = 0; nt < 4; ++nt) {
        float e = __expf(s[nt][rr] - vmax);
        ssum += e;
        *(ushort*)(smem + OFF_QK + (hl2 * 64 + qrow) * 128 + SWZ(qrow, (nt * 16 + l16) * 2)) = f2bf(e);
      }
      ssum += __shfl_xor(ssum, 1);
      ssum += __shfl_xor(ssum, 2);
      ssum += __shfl_xor(ssum, 4);
      ssum += __shfl_xor(ssum, 8);
      rcp_[rr] = 1.f / ssum;
    }

    // ---- PV: O[16 rows][32 d] per wave (P rows same-wave; vT covered by (b))
    f32x4 o[2];
    o[0] = f32x4{0.f, 0.f, 0.f, 0.f};
    o[1] = f32x4{0.f, 0.f, 0.f, 0.f};
    #pragma unroll
    for (int kk = 0; kk < 2; ++kk) {
      const int r = r0 + l16;
      bf16x8 pf = *(const bf16x8*)(smem + OFF_QK + (hl2 * 64 + r) * 128 + SWZ(r, kk * 64 + lq * 16));
      #pragma unroll
      for (int nt = 0; nt < 2; ++nt) {
        const int vr = nt * 16 + l16;
        bf16x8 vf = *(const bf16x8*)(smem + OFF_VT + (hl2 * 32 + vr) * 128 + SWZ(vr, kk * 64 + lq * 16));
        o[nt] = MFMA16(pf, vf, o[nt]);
      }
    }
    __syncthreads();  // (c1) vT reads done -> o4 overlays vt

    #pragma unroll
    for (int nt = 0; nt < 2; ++nt)
      #pragma unroll
      for (int rr = 0; rr < 4; ++rr) {
        const int tok = r0 + lq * 4 + rr;
        const int col = hl2 * 32 + nt * 16 + l16;   // channel within pair (0..63)
        *(ushort*)(smem + OFF_VT + tok * 128 + SWZ(tok, col * 2)) = f2bf(o[nt][rr] * rcp_[rr]);
      }
    __syncthreads();  // (c2) o4 ready

    // ---- proj partial: oacc += O4[64, pass*64..+64] x projW^T slice
    #pragma unroll
    for (int kk = 0; kk < 2; ++kk) {
      bf16x8 af[4];
      #pragma unroll
      for (int m = 0; m < 4; ++m) {
        const int r = m * 16 + l16;
        af[m] = *(const bf16x8*)(smem + OFF_VT + r * 128 + SWZ(r, kk * 64 + lq * 16));
      }
      #pragma unroll
      for (int nt = 0; nt < 2; ++nt) {
        const int c = wave * 32 + nt * 16 + l16;
        bf16x8 bfr = *(const bf16x8*)(projw + (size_t)c * 256 + pass * 64 + kk * 32 + lq * 8);
        #pragma unroll
        for (int m = 0; m < 4; ++m)
          oacc[m][nt] = MFMA16(af[m], bfr, oacc[m][nt]);
      }
    }
  }  // pass

  // ---- epilogue: +proj_b, through 32KB LDS half-tiles, coalesced float4 stores
  #pragma unroll 1
  for (int half = 0; half < 2; ++half) {
    __syncthreads();  // region [0,32768) free (xw dead / prev half stored)
    if ((wave >> 2) == half) {
      // waves [half*4, half*4+4) own cols [half*128, +128)
      #pragma unroll
      for (int nt = 0; nt < 2; ++nt) {
        const int col = wave * 32 + nt * 16 + l16;       // global col
        const float pb = proj_b[col];
        const int lc = col & 127;                        // col within half
        #pragma unroll
        for (int m = 0; m < 4; ++m)
          #pragma unroll
          for (int rr = 0; rr < 4; ++rr) {
            const int row = m * 16 + lq * 4 + rr;
            *(float*)(smem + row * 512 + SWZ(row, lc * 4)) = oacc[m][nt][rr] + pb;
          }
      }
    }
    __syncthreads();
    #pragma unroll
    for (int it = 0; it < 4; ++it) {
      const int idx = it * 512 + tid;
      const int row = idx >> 5, c4 = idx & 31;
      const int gr = wy * 8 + (row >> 3);
      const int gc = wx * 8 + (row & 7);
      if (gr < 250 && gc < 250) {
        float4 v = *(const float4*)(smem + row * 512 + SWZ(row, c4 * 16));
        *(float4*)(out + ((size_t)bb_ * 62500 + (size_t)gr * 250 + gc) * 256 + half * 128 + c4 * 4) = v;
      }
    }
  }
}

extern "C" void kernel_launch(void* const* d_in, const int* in_sizes, int n_in,
                              void* d_out, int out_size, void* d_ws, size_t ws_size,
                              hipStream_t stream) {
  const float* x        = (const float*)d_in[0];
  const float* qkv_w    = (const float*)d_in[1];
  const float* proj_w   = (const float*)d_in[2];
  const float* proj_b   = (const float*)d_in[3];
  const float* rel_bias = (const float*)d_in[4];
  float* out = (float*)d_out;
  ushort* wsb = (ushort*)d_ws;  // [0,196608): qkv_w bf16; [196608,262144): proj_w bf16

  (void)in_sizes; (void)n_in; (void)out_size; (void)ws_size;

  hipFuncSetAttribute((const void*)swin_fused_kernel,
                      hipFuncAttributeMaxDynamicSharedMemorySize, LDS_TOTAL);

  convert_w_kernel<<<1024, 256, 0, stream>>>(qkv_w, proj_w, wsb);
  swin_fused_kernel<<<8192, 512, LDS_TOTAL, stream>>>(x, wsb, wsb + NQKV, proj_b,
                                                      rel_bias, out);
}